// Round 3
// baseline (14.587 us; speedup 1.0000x reference)
//
#include <hip/hip_runtime.h>
#include <hip/hip_bf16.h>

// GraphAttentionLayer_8804682957287
//
// Reference applies softmax to the CONSTANT zero_vec (-9e15) => attention is
// uniform 1/N, so out[i,:] = relu(((colsum h) @ W)/N), identical for all rows.
// adj (256 MB) and a are dead. Traffic: read h (16 MB) + W, write out (2 MB).
//
// Round 3: raise K1 occupancy (512 blocks x 512 thr = 16 waves/CU, was 8),
// halve K2's redundant partial reads (128 blocks x 64 rows each).

constexpr int NROWS = 8192;
constexpr int FIN   = 512;
constexpr int FOUT  = 64;

constexpr int BLOCKS1        = 512;
constexpr int ROWS_PER_B1    = NROWS / BLOCKS1;   // 16
constexpr int BLOCKS2        = 128;
constexpr int ROWS_PER_B2    = NROWS / BLOCKS2;   // 64

// ---------------------------------------------------------------------------
// K1: colsum of 16 rows + 512x64 projection, per block. 512 threads.
// Colsum: (j = float4-col 0..127, ty = row phase 0..3), 4 float4 loads/thread.
// Projection: (t = out-col 0..63, ch = chunk 0..7 covering 64 c-values).
// Writes 64-float partial y per block.
// ---------------------------------------------------------------------------
__global__ __launch_bounds__(512) void colsum_project_k(
    const float4* __restrict__ h4, const float* __restrict__ W,
    float* __restrict__ ypart)
{
    const int tid = threadIdx.x;
    const int b   = blockIdx.x;

    // --- colsum of this block's 16 rows ---
    const int j  = tid & 127;
    const int ty = tid >> 7;          // 0..3

    const float4* p = h4 + (size_t)(b * ROWS_PER_B1 + ty) * (FIN / 4) + j;
    float4 acc = make_float4(0.f, 0.f, 0.f, 0.f);
    #pragma unroll
    for (int k = 0; k < ROWS_PER_B1 / 4; ++k) {      // 4 rows, stride 4
        float4 v = p[(size_t)(4 * k) * (FIN / 4)];
        acc.x += v.x; acc.y += v.y; acc.z += v.z; acc.w += v.w;
    }

    __shared__ float4 sm4[512];
    sm4[tid] = acc;
    __syncthreads();

    __shared__ float s[FIN];          // reduced column sums
    if (ty == 0) {
        float4 a0 = sm4[j], a1 = sm4[128 + j], a2 = sm4[256 + j], a3 = sm4[384 + j];
        s[4 * j + 0] = a0.x + a1.x + a2.x + a3.x;
        s[4 * j + 1] = a0.y + a1.y + a2.y + a3.y;
        s[4 * j + 2] = a0.z + a1.z + a2.z + a3.z;
        s[4 * j + 3] = a0.w + a1.w + a2.w + a3.w;
    }
    __syncthreads();

    // --- projection: y_b[t] = sum_c s[c] * W[c*64 + t], split over 8 chunks ---
    const int t  = tid & 63;
    const int ch = tid >> 6;          // 0..7
    const int c0 = ch * 64;

    float y = 0.f;
    #pragma unroll 8
    for (int i = 0; i < 64; ++i)
        y += s[c0 + i] * W[(c0 + i) * FOUT + t];

    __shared__ float yp[8 * FOUT];
    yp[ch * FOUT + t] = y;
    __syncthreads();

    if (tid < FOUT) {
        float v = 0.f;
        #pragma unroll
        for (int k = 0; k < 8; ++k)
            v += yp[k * FOUT + tid];
        ypart[b * FOUT + tid] = v;
    }
}

// ---------------------------------------------------------------------------
// K2: every block reduces the 512x64 partials identically (deterministic fp32
// order -> bitwise-identical vec), relu(/N), writes its 64 rows of output.
// ---------------------------------------------------------------------------
__global__ __launch_bounds__(512) void finalize_broadcast_k(
    const float* __restrict__ ypart, float4* __restrict__ out4)
{
    const int tid = threadIdx.x;
    const int g   = blockIdx.x;

    // Phase A: thread (t, ch) sums 64 of the 512 block-partials for column t.
    const int t  = tid & 63;
    const int ch = tid >> 6;          // 0..7 chunks of 64 blocks

    float acc = 0.f;
    #pragma unroll 8
    for (int k = 0; k < 64; ++k)
        acc += ypart[(ch * 64 + k) * FOUT + t];

    __shared__ float yp[8 * FOUT];
    yp[ch * FOUT + t] = acc;
    __syncthreads();

    // Phase B: threads 0..63 finish the sum in fixed order, relu(/N).
    __shared__ float4 vec4[FOUT / 4];
    if (tid < FOUT) {
        float v = 0.f;
        #pragma unroll
        for (int k = 0; k < 8; ++k)
            v += yp[k * FOUT + tid];
        v *= (1.0f / (float)NROWS);
        ((float*)vec4)[tid] = v > 0.f ? v : 0.f;
    }
    __syncthreads();

    // Phase C: write 64 rows x 16 float4 = 1024 float4 per block.
    #pragma unroll
    for (int i = 0; i < 2; ++i)
        out4[(size_t)g * 1024 + i * 512 + tid] = vec4[tid & 15];
}

extern "C" void kernel_launch(void* const* d_in, const int* in_sizes, int n_in,
                              void* d_out, int out_size, void* d_ws, size_t ws_size,
                              hipStream_t stream)
{
    const float* h = (const float*)d_in[0];   // (8192, 512)
    // d_in[1] = adj (8192, 8192) — DEAD, never read
    const float* W = (const float*)d_in[2];   // (512, 64) row-major
    // d_in[3] = a (128, 1)        — DEAD (e is unused by the output)

    float* ypart = (float*)d_ws;              // 512*64 floats = 128 KB

    colsum_project_k<<<BLOCKS1, 512, 0, stream>>>(
        (const float4*)h, W, ypart);
    finalize_broadcast_k<<<BLOCKS2, 512, 0, stream>>>(
        ypart, (float4*)d_out);
}